// Round 12
// baseline (61.467 us; speedup 1.0000x reference)
//
#include <hip/hip_runtime.h>
#include <hip/hip_bf16.h>

typedef short short8 __attribute__((ext_vector_type(8)));
typedef short short4v __attribute__((ext_vector_type(4)));
typedef float float4v __attribute__((ext_vector_type(4)));
typedef float f32x4 __attribute__((ext_vector_type(4)));

#define NEG_HUGE (-1e30f)
#define QK_SCALE 0.1803368801111204f  /* 0.125 * log2(e) */

__device__ __forceinline__ unsigned short f2bf(float f) {
  union { __hip_bfloat16 h; unsigned short u; } c;
  c.h = __float2bfloat16(f);
  return c.u;
}

#define MFMA16(a, b, c) __builtin_amdgcn_mfma_f32_16x16x32_bf16((a), (b), (c), 0, 0, 0)

// ---------------------------------------------------------------------------
// Kernel 0: W [1024][64] fp32 (x3) -> Wt [3][64][1024] bf16 (transposed).
// Wq additionally scaled by 0.125*log2(e) so attn works in exp2 domain.
// ---------------------------------------------------------------------------
__global__ __launch_bounds__(256) void wtrans_kernel(
    const float* __restrict__ Wk, const float* __restrict__ Wq,
    const float* __restrict__ Wv, unsigned short* __restrict__ Wt) {
  int mat = blockIdx.x >> 4, kb = blockIdx.x & 15;
  const float* W = (mat == 0) ? Wk : ((mat == 1) ? Wq : Wv);
  float qscale = (mat == 1) ? QK_SCALE : 1.0f;
  __shared__ float tile[64][65];
  int tid = threadIdx.x;
  int n = tid & 63, k0 = tid >> 6;
#pragma unroll
  for (int i = 0; i < 16; i++) {
    int k = i * 4 + k0;
    tile[k][n] = W[(kb * 64 + k) * 64 + n];
  }
  __syncthreads();
  int n2 = tid >> 2, c = tid & 3;
  unsigned short tmp[16];
#pragma unroll
  for (int j = 0; j < 16; j++) tmp[j] = f2bf(tile[c * 16 + j][n2] * qscale);
  unsigned short* dst = Wt + (mat * 64 + n2) * 1024 + kb * 64 + c * 16;
  *(short8*)dst = *(short8*)tmp;
  *(short8*)(dst + 8) = *(short8*)(tmp + 8);
}

// ---------------------------------------------------------------------------
// Kernel 1: projection v6 (2-phase, raw barriers, counted waits implicit).
// x[16384][1024] fp32 @ Wt[3][64][1024] bf16 -> Kb/Qb bf16, Vt (sigma-perm).
// BM=64, BK=128 (8 iters), grid 256 = 1 block/CU, 512 thr = 8 waves
// (wm 0..3 x wn 0..1). 128KB DYNAMIC LDS double-buffer, T2 XOR swizzle
// (chunk ^= row&7 on 16B chunks). Raw s_barrier + lgkmcnt(0) ONLY -> global
// prefetch loads stay in flight across the barrier (no vmcnt drain).
// x prefetch depth 2 (HBM ~900cy covered); W depth 1 (L2-hot).
// ---------------------------------------------------------------------------
__global__ __launch_bounds__(512) void proj_kernel(
    const float* __restrict__ x, const unsigned short* __restrict__ Wt,
    unsigned short* __restrict__ Kb, unsigned short* __restrict__ Qb,
    unsigned short* __restrict__ Vt) {
  extern __shared__ unsigned short smem[];
  // layout: x bufs [2][64*128] at 0, 8192; W bufs [2][192*128] at 16384, 40960
  int tid = threadIdx.x;
  int w = tid >> 6, lane = tid & 63;
  int wm = w >> 1, wn = w & 1;
  int g = lane >> 4, r = lane & 15;
  int row0 = blockIdx.x * 64;

  // x staging: row xr (0..63), 16-float chunk xc (0..7) -> 2 LDS 16B chunks
  int xr = tid >> 3, xc = tid & 7;
  const float* xp = &x[(size_t)(row0 + xr) * 1024 + xc * 16];
  int xe0 = xr * 128 + (((xc * 2 + 0) ^ (xr & 7)) << 3);
  int xe1 = xr * 128 + (((xc * 2 + 1) ^ (xr & 7)) << 3);
  // W staging: 6 chunks/thread: row wr (0..191), chunk wc (0..15)
  const unsigned short* wp[6];
  int we[6];
#pragma unroll
  for (int i = 0; i < 6; i++) {
    int idx = tid + i * 512;
    int wr = idx >> 4, wc = idx & 15;
    wp[i] = &Wt[(size_t)wr * 1024 + wc * 8];
    we[i] = wr * 128 + (((wc ^ (wr & 7))) << 3);
  }
  int fsw = r & 7;  // fragment-read swizzle

  f32x4 acc[6];
#pragma unroll
  for (int nf = 0; nf < 6; nf++) acc[nf] = (f32x4){0.f, 0.f, 0.f, 0.f};

  float4v x0[4], x1[4];
  short8 wv[6];
  // prologue: x(0)->x0, x(1)->x1, W(0)->wv; write tile 0 to buf 0
#pragma unroll
  for (int j = 0; j < 4; j++) x0[j] = *(const float4v*)(xp + j * 4);
#pragma unroll
  for (int j = 0; j < 4; j++) x1[j] = *(const float4v*)(xp + 128 + j * 4);
#pragma unroll
  for (int i = 0; i < 6; i++) wv[i] = *(const short8*)(wp[i]);
  {
    unsigned short t16[16];
#pragma unroll
    for (int j = 0; j < 4; j++)
#pragma unroll
      for (int e = 0; e < 4; e++) t16[j * 4 + e] = f2bf(x0[j][e]);
    *(short8*)&smem[xe0] = *(short8*)&t16[0];
    *(short8*)&smem[xe1] = *(short8*)&t16[8];
#pragma unroll
    for (int i = 0; i < 6; i++) *(short8*)&smem[16384 + we[i]] = wv[i];
  }
  asm volatile("s_waitcnt lgkmcnt(0)" ::: "memory");
  __builtin_amdgcn_s_barrier();

  for (int t = 0; t < 8; t++) {
    int cur = t & 1;
    unsigned short* xl = smem + cur * 8192;
    unsigned short* wl = smem + 16384 + cur * 24576;
    // issue W(t+1) (depth 1, L2) and x(t+2) (depth 2, HBM)
    if (t < 7) {
      int k0 = (t + 1) * 128;
#pragma unroll
      for (int i = 0; i < 6; i++) wv[i] = *(const short8*)(wp[i] + k0);
    }
    float4v xn[4];
    if (t < 6) {
      int k0 = (t + 2) * 128;
#pragma unroll
      for (int j = 0; j < 4; j++) xn[j] = *(const float4v*)(xp + k0 + j * 4);
    }
    // compute tile t from buf cur
#pragma unroll
    for (int ks = 0; ks < 4; ks++) {
      short8 af = *(short8*)&xl[(wm * 16 + r) * 128 + (((ks * 4 + g) ^ fsw) << 3)];
#pragma unroll
      for (int nf = 0; nf < 6; nf++) {
        short8 bf = *(short8*)&wl[(wn * 96 + nf * 16 + r) * 128 + (((ks * 4 + g) ^ fsw) << 3)];
        acc[nf] = MFMA16(af, bf, acc[nf]);
      }
    }
    // stage tile t+1 into buf cur^1 (auto vmcnt waits only what's needed)
    if (t < 7) {
      unsigned short* xl1 = smem + (cur ^ 1) * 8192;
      unsigned short* wl1 = smem + 16384 + (cur ^ 1) * 24576;
      unsigned short t16[16];
#pragma unroll
      for (int j = 0; j < 4; j++)
#pragma unroll
        for (int e = 0; e < 4; e++) t16[j * 4 + e] = f2bf(x1[j][e]);
      *(short8*)&xl1[xe0] = *(short8*)&t16[0];
      *(short8*)&xl1[xe1] = *(short8*)&t16[8];
#pragma unroll
      for (int i = 0; i < 6; i++) *(short8*)&wl1[we[i]] = wv[i];
    }
    // rotate x batches
#pragma unroll
    for (int j = 0; j < 4; j++) x1[j] = xn[j];
    asm volatile("s_waitcnt lgkmcnt(0)" ::: "memory");
    __builtin_amdgcn_s_barrier();
  }
  // epilogue: row = row0 + wm*16 + g*4 + reg, col = wn*96 + nf*16 + r
#pragma unroll
  for (int nf = 0; nf < 6; nf++) {
    int col = wn * 96 + nf * 16 + r;
    if (col < 128) {
      int mat = col >> 6, h = col & 63;
      unsigned short* dst = (mat == 0) ? Kb : Qb;
#pragma unroll
      for (int reg = 0; reg < 4; reg++) {
        int grow = row0 + wm * 16 + g * 4 + reg;
        dst[(size_t)grow * 64 + h] = f2bf(acc[nf][reg]);
      }
    } else {
      int h = col & 63;
      int grow0 = row0 + wm * 16 + g * 4;
      unsigned short t4[4];
#pragma unroll
      for (int reg = 0; reg < 4; reg++) t4[reg] = f2bf(acc[nf][reg]);
      // sigma permutation within the 64-row block (reg stays contiguous)
      int kv6 = grow0 & 63;
      int nfb = (kv6 >> 4) & 3, gb = (kv6 >> 2) & 3;
      int s0 = (nfb >> 1) * 32 + gb * 8 + (nfb & 1) * 4;
      size_t off = ((size_t)(grow0 >> 12) * 64 + h) * 4096 +
                   ((size_t)(grow0 & 4095) & ~(size_t)63) + s0;
      *(short4v*)&Vt[off] = *(short4v*)t4;
    }
  }
}

// ---------------------------------------------------------------------------
// Kernel 2: causal flash attention v8 (= v6 loop + colocation-balanced qt).
// grid 512, 256 thr = 4 waves kv-split (t%4==w), 32-row q-tile.
// Blocks bi and bi+256 co-reside on the same CU (observed round-robin
// dispatch); qt = (iq<64) ? 64+iq : 127-iq makes each colocated pair's
// ntiles sum exactly 65 -> uniform per-CU work, heavy blocks dispatched
// first. Swapped QK^T + swapped PV with pi-permuted V; P in registers.
// V loads issued AFTER QK^T so their latency hides under softmax.
// ---------------------------------------------------------------------------
__global__ __launch_bounds__(256, 3) void attn_kernel(
    const unsigned short* __restrict__ Kb, const unsigned short* __restrict__ Qb,
    const unsigned short* __restrict__ VtB, float* __restrict__ out) {
  __shared__ float O_l[4][32][68];
  __shared__ float st_l[4][32][2];
  int tid = threadIdx.x;
  int w = tid >> 6, lane = tid & 63;
  int g = lane >> 4, r = lane & 15;
  int bi = blockIdx.x;
  int b = bi & 3, iq = bi >> 2;           // iq 0..127
  int qt = (iq < 64) ? (64 + iq) : (127 - iq);
  int qabs = qt * 32;
  const unsigned short* Kp = Kb + (size_t)b * 4096 * 64;
  const unsigned short* Qp = Qb + (size_t)b * 4096 * 64;
  const unsigned short* Vp = VtB + (size_t)b * 64 * 4096;

  // Q B-operand frags: B[q=mf*16+r][k=h=ks*32+g*8+j]
  short8 qa[2][2];
#pragma unroll
  for (int mf = 0; mf < 2; mf++)
#pragma unroll
    for (int ks = 0; ks < 2; ks++)
      qa[mf][ks] = *(const short8*)&Qp[(size_t)(qabs + mf * 16 + r) * 64 + ks * 32 + g * 8];

  float m_st[2] = {NEG_HUGE, NEG_HUGE};
  float l_ln[2] = {0.f, 0.f};        // per-lane partial row sums
  f32x4 o[4][2];                      // o[nfh][mf]
#pragma unroll
  for (int nfh = 0; nfh < 4; nfh++)
#pragma unroll
    for (int mf = 0; mf < 2; mf++) o[nfh][mf] = (f32x4){0.f, 0.f, 0.f, 0.f};

  int ntiles = (qabs >> 6) + 1;
  for (int t = w; t < ntiles; t += 4) {
    int kvb = t << 6;
    // ---- S^T = K Q^T, K loaded JIT per ks-half ----
    f32x4 s[4][2];
#pragma unroll
    for (int nf = 0; nf < 4; nf++)
#pragma unroll
      for (int mf = 0; mf < 2; mf++) s[nf][mf] = (f32x4){0.f, 0.f, 0.f, 0.f};
#pragma unroll
    for (int ks = 0; ks < 2; ks++) {
      short8 kf[4];
#pragma unroll
      for (int nf = 0; nf < 4; nf++)
        kf[nf] = *(const short8*)&Kp[(size_t)(kvb + nf * 16 + r) * 64 + ks * 32 + g * 8];
#pragma unroll
      for (int nf = 0; nf < 4; nf++) {
        s[nf][0] = MFMA16(kf[nf], qa[0][ks], s[nf][0]);
        s[nf][1] = MFMA16(kf[nf], qa[1][ks], s[nf][1]);
      }
    }
    // ---- V A-fragments issued here: latency hides under softmax ----
    short8 vf[2][4];
#pragma unroll
    for (int ks = 0; ks < 2; ks++)
#pragma unroll
      for (int nfh = 0; nfh < 4; nfh++)
        vf[ks][nfh] = *(const short8*)&Vp[(size_t)(nfh * 16 + r) * 4096 + kvb + ks * 32 + g * 8];
    // ---- causal mask (final tile only) ----
    if (kvb + 63 > qabs) {
#pragma unroll
      for (int mf = 0; mf < 2; mf++) {
        int q = qabs + mf * 16 + r;
#pragma unroll
        for (int nf = 0; nf < 4; nf++)
#pragma unroll
          for (int reg = 0; reg < 4; reg++) {
            int kv = kvb + nf * 16 + g * 4 + reg;
            if (kv > q) s[nf][mf][reg] = NEG_HUGE;
          }
      }
    }
    // ---- row max (in-lane 16 + xor16/xor32), alpha ----
    float alpha[2];
#pragma unroll
    for (int mf = 0; mf < 2; mf++) {
      float m0 = fmaxf(fmaxf(fmaxf(s[0][mf][0], s[0][mf][1]), fmaxf(s[0][mf][2], s[0][mf][3])),
                       fmaxf(fmaxf(s[1][mf][0], s[1][mf][1]), fmaxf(s[1][mf][2], s[1][mf][3])));
      float m1 = fmaxf(fmaxf(fmaxf(s[2][mf][0], s[2][mf][1]), fmaxf(s[2][mf][2], s[2][mf][3])),
                       fmaxf(fmaxf(s[3][mf][0], s[3][mf][1]), fmaxf(s[3][mf][2], s[3][mf][3])));
      float m0a = fmaxf(m0, m1);
      m0a = fmaxf(m0a, __shfl_xor(m0a, 16));
      m0a = fmaxf(m0a, __shfl_xor(m0a, 32));
      float mn = fmaxf(m_st[mf], m0a);
      alpha[mf] = exp2f(m_st[mf] - mn);
      m_st[mf] = mn;
    }
    // ---- P = exp2(S - m) in-place; per-lane partial sums; rescale O ----
#pragma unroll
    for (int mf = 0; mf < 2; mf++) {
      float rs = 0.f;
#pragma unroll
      for (int nf = 0; nf < 4; nf++)
#pragma unroll
        for (int reg = 0; reg < 4; reg++) {
          float p = exp2f(s[nf][mf][reg] - m_st[mf]);
          s[nf][mf][reg] = p;
          rs += p;
        }
      l_ln[mf] = l_ln[mf] * alpha[mf] + rs;
#pragma unroll
      for (int nfh = 0; nfh < 4; nfh++)
#pragma unroll
        for (int reg = 0; reg < 4; reg++) o[nfh][mf][reg] *= alpha[mf];
    }
    // ---- pack P lane-locally (pi layout) and PV ----
#pragma unroll
    for (int ks = 0; ks < 2; ks++)
#pragma unroll
      for (int mf = 0; mf < 2; mf++) {
        union { unsigned u[4]; short8 v; } pb;
        asm("v_cvt_pk_bf16_f32 %0, %1, %2" : "=v"(pb.u[0]) : "v"(s[2 * ks][mf][0]), "v"(s[2 * ks][mf][1]));
        asm("v_cvt_pk_bf16_f32 %0, %1, %2" : "=v"(pb.u[1]) : "v"(s[2 * ks][mf][2]), "v"(s[2 * ks][mf][3]));
        asm("v_cvt_pk_bf16_f32 %0, %1, %2" : "=v"(pb.u[2]) : "v"(s[2 * ks + 1][mf][0]), "v"(s[2 * ks + 1][mf][1]));
        asm("v_cvt_pk_bf16_f32 %0, %1, %2" : "=v"(pb.u[3]) : "v"(s[2 * ks + 1][mf][2]), "v"(s[2 * ks + 1][mf][3]));
#pragma unroll
        for (int nfh = 0; nfh < 4; nfh++)
          o[nfh][mf] = MFMA16(vf[ks][nfh], pb.v, o[nfh][mf]);
      }
  }
  // ---- finalize l (deferred reduction) ----
#pragma unroll
  for (int mf = 0; mf < 2; mf++) {
    float s0 = l_ln[mf];
    s0 += __shfl_xor(s0, 16);
    s0 += __shfl_xor(s0, 32);
    l_ln[mf] = s0;
  }
  // ---- cross-wave merge: store [q][h] (q = mf*16+r, h = nfh*16+g*4+reg) ----
  __syncthreads();
#pragma unroll
  for (int nfh = 0; nfh < 4; nfh++)
#pragma unroll
    for (int mf = 0; mf < 2; mf++)
      *(f32x4*)&O_l[w][mf * 16 + r][nfh * 16 + g * 4] = o[nfh][mf];
  if (g == 0) {
#pragma unroll
    for (int mf = 0; mf < 2; mf++) {
      st_l[w][mf * 16 + r][0] = m_st[mf];
      st_l[w][mf * 16 + r][1] = l_ln[mf];
    }
  }
  __syncthreads();
  {
    int row = tid >> 3, cg = tid & 7;   // row = q (0..31), cg*8 = h block
    float mw[4], lw[4];
#pragma unroll
    for (int ww = 0; ww < 4; ww++) {
      mw[ww] = st_l[ww][row][0];
      lw[ww] = st_l[ww][row][1];
    }
    float mstar = fmaxf(fmaxf(mw[0], mw[1]), fmaxf(mw[2], mw[3]));
    float sc[4], lstar = 0.f;
#pragma unroll
    for (int ww = 0; ww < 4; ww++) { sc[ww] = exp2f(mw[ww] - mstar); lstar += sc[ww] * lw[ww]; }
    float inv = 1.0f / lstar;
    float a0[8];
#pragma unroll
    for (int cc = 0; cc < 8; cc++) a0[cc] = 0.f;
#pragma unroll
    for (int ww = 0; ww < 4; ww++) {
      f32x4 v0 = *(f32x4*)&O_l[ww][row][cg * 8];
      f32x4 v1 = *(f32x4*)&O_l[ww][row][cg * 8 + 4];
#pragma unroll
      for (int e = 0; e < 4; e++) { a0[e] += sc[ww] * v0[e]; a0[4 + e] += sc[ww] * v1[e]; }
    }
    float4v o0, o1;
#pragma unroll
    for (int e = 0; e < 4; e++) { o0[e] = a0[e] * inv; o1[e] = a0[4 + e] * inv; }
    float* op = &out[((size_t)b * 4096 + qabs + row) * 64 + cg * 8];
    *(float4v*)op = o0;
    *(float4v*)(op + 4) = o1;
  }
}

// ---------------------------------------------------------------------------
extern "C" void kernel_launch(void* const* d_in, const int* in_sizes, int n_in,
                              void* d_out, int out_size, void* d_ws, size_t ws_size,
                              hipStream_t stream) {
  (void)in_sizes; (void)n_in; (void)out_size; (void)ws_size;
  const float* x  = (const float*)d_in[0];
  const float* Wk = (const float*)d_in[1];
  const float* Wq = (const float*)d_in[2];
  const float* Wv = (const float*)d_in[3];
  float* out = (float*)d_out;
  char* ws = (char*)d_ws;

  unsigned short* Wt = (unsigned short*)ws;                       // 384KB
  unsigned short* Kb = (unsigned short*)(ws + (512u << 10));      // 2MB
  unsigned short* Qb = (unsigned short*)(ws + (512u << 10) + (2u << 20));
  unsigned short* Vt = (unsigned short*)(ws + (512u << 10) + (4u << 20));

  wtrans_kernel<<<48, 256, 0, stream>>>(Wk, Wq, Wv, Wt);
  proj_kernel<<<256, 512, 131072, stream>>>(x, Wt, Kb, Qb, Vt);
  attn_kernel<<<512, 256, 0, stream>>>(Kb, Qb, Vt, out);
}

// Round 13
// 57.891 us; speedup vs baseline: 1.0618x; 1.0618x over previous
//
#include <hip/hip_runtime.h>
#include <hip/hip_bf16.h>

typedef short short8 __attribute__((ext_vector_type(8)));
typedef short short4v __attribute__((ext_vector_type(4)));
typedef float float4v __attribute__((ext_vector_type(4)));
typedef float f32x4 __attribute__((ext_vector_type(4)));

#define NEG_HUGE (-1e30f)
#define QK_SCALE 0.1803368801111204f  /* 0.125 * log2(e) */

__device__ __forceinline__ unsigned short f2bf(float f) {
  union { __hip_bfloat16 h; unsigned short u; } c;
  c.h = __float2bfloat16(f);
  return c.u;
}

#define MFMA16(a, b, c) __builtin_amdgcn_mfma_f32_16x16x32_bf16((a), (b), (c), 0, 0, 0)

// global_load_lds: 16B per lane, LDS dest = uniform base + lane*16.
#define GLL(gp, lp) __builtin_amdgcn_global_load_lds( \
    (const __attribute__((address_space(1))) unsigned int*)(const void*)(gp), \
    (__attribute__((address_space(3))) unsigned int*)(void*)(lp), 16, 0, 0)

// ---------------------------------------------------------------------------
// Kernel 0: W [1024][64] fp32 (x3) -> Wt [3][64][1024] bf16 (transposed),
// stored with per-64-elem-k-tile chunk swizzle: 16B chunk l of k-tile kb in
// row n lands at position l ^ (n&7). proj's gload_lds then stages linearly
// and the LDS comes out bank-conflict-free for b128 fragment reads.
// Wq additionally scaled by 0.125*log2(e) so attn works in exp2 domain.
// ---------------------------------------------------------------------------
__global__ __launch_bounds__(256) void wtrans_kernel(
    const float* __restrict__ Wk, const float* __restrict__ Wq,
    const float* __restrict__ Wv, unsigned short* __restrict__ Wt) {
  int mat = blockIdx.x >> 4, kb = blockIdx.x & 15;
  const float* W = (mat == 0) ? Wk : ((mat == 1) ? Wq : Wv);
  float qscale = (mat == 1) ? QK_SCALE : 1.0f;
  __shared__ float tile[64][65];
  int tid = threadIdx.x;
  int n = tid & 63, k0 = tid >> 6;
#pragma unroll
  for (int i = 0; i < 16; i++) {
    int k = i * 4 + k0;
    tile[k][n] = W[(kb * 64 + k) * 64 + n];
  }
  __syncthreads();
  int n2 = tid >> 2, c = tid & 3;
  unsigned short tmp[16];
#pragma unroll
  for (int j = 0; j < 16; j++) tmp[j] = f2bf(tile[c * 16 + j][n2] * qscale);
  unsigned short* rowp = Wt + (mat * 64 + n2) * 1024 + kb * 64;
  int s = n2 & 7;
  *(short8*)(rowp + ((c * 2) ^ s) * 8) = *(short8*)tmp;
  *(short8*)(rowp + ((c * 2 + 1) ^ s) * 8) = *(short8*)(tmp + 8);
}

// ---------------------------------------------------------------------------
// Kernel 1: projection v7 (m97-style global_load_lds + counted vmcnt).
// x[16384][1024] fp32 @ Wt[3][64][1024] bf16(swizzled) -> Kb/Qb bf16,
// Vt (sigma-permuted). BM=64, BK=64 (16 iters), grid 256, 512 thr = 8 waves
// (wm 0..3 x wn 0..1). LDS: x fp32 triple-buffer 3x16KB + W dbuf 2x24KB
// = 96KB dynamic. x staged via source-XOR (chunk p of row rr <- global
// chunk p^(rr&7)); W pre-swizzled in global by wtrans. Fragment reads
// apply the same XOR -> ~2-way banks (free). x converted fp32->bf16 at
// read time via v_cvt_pk_bf16_f32. vmcnt(2) per iter (x depth-2 in flight).
// ---------------------------------------------------------------------------
__global__ __launch_bounds__(512) void proj_kernel(
    const float* __restrict__ x, const unsigned short* __restrict__ Wt,
    unsigned short* __restrict__ Kb, unsigned short* __restrict__ Qb,
    unsigned short* __restrict__ Vt) {
  extern __shared__ char smem[];  // [0,49152): x bufs x3; [49152,98304): W x2
  int tid = threadIdx.x;
  int w = tid >> 6, lane = tid & 63;
  int wm = w >> 1, wn = w & 1;
  int g = lane >> 4, r = lane & 15;
  int row0 = blockIdx.x * 64;

  // x staging: chunk l = i*512+tid of 1024; row rr=l>>4, pos p=l&15 holds
  // global chunk p^(rr&7) of row rr. byte src = row*4096 + k*4 + chunk*16.
  long xoff[2];
  unsigned xl_u[2];
#pragma unroll
  for (int i = 0; i < 2; i++) {
    int l = i * 512 + tid;
    int rr = l >> 4, p = l & 15;
    xoff[i] = (long)(row0 + rr) * 4096 + ((p ^ (rr & 7)) * 16);
    xl_u[i] = i * 8192 + w * 1024;
  }
  // W staging (global pre-swizzled -> linear): chunk l=i*512+tid of 1536;
  // row=l>>3, c=l&7; src byte = row*2048 + t*128 + c*16.
  long woff[3];
  unsigned wl_u[3];
#pragma unroll
  for (int i = 0; i < 3; i++) {
    int l = i * 512 + tid;
    woff[i] = (long)(l >> 3) * 2048 + (l & 7) * 16;
    wl_u[i] = i * 8192 + w * 1024;
  }
  const char* xg = (const char*)x;
  const char* wg = (const char*)Wt;

  f32x4 acc[6];
#pragma unroll
  for (int nf = 0; nf < 6; nf++) acc[nf] = (f32x4){0.f, 0.f, 0.f, 0.f};

  // prologue: W(0)->wbuf0, x(0)->xbuf0, x(1)->xbuf1
  {
    char* wb = smem + 49152;
#pragma unroll
    for (int i = 0; i < 3; i++) GLL(wg + woff[i], wb + wl_u[i]);
    char* xb0 = smem;
#pragma unroll
    for (int i = 0; i < 2; i++) GLL(xg + xoff[i], xb0 + xl_u[i]);
    char* xb1 = smem + 16384;
#pragma unroll
    for (int i = 0; i < 2; i++) GLL(xg + xoff[i] + 256, xb1 + xl_u[i]);
  }
  asm volatile("s_waitcnt vmcnt(2)" ::: "memory");
  __builtin_amdgcn_s_barrier();

  int rs7 = r & 7;
  for (int t = 0; t < 16; t++) {
    // issue W(t+1) depth-1, x(t+2) depth-2 (stay in flight across barrier)
    if (t < 15) {
      char* wb = smem + 49152 + ((t + 1) & 1) * 24576;
      long ko = (long)(t + 1) * 128;
#pragma unroll
      for (int i = 0; i < 3; i++) GLL(wg + woff[i] + ko, wb + wl_u[i]);
    }
    if (t < 14) {
      char* xb = smem + ((t + 2) % 3) * 16384;
      long ko = (long)(t + 2) * 256;
#pragma unroll
      for (int i = 0; i < 2; i++) GLL(xg + xoff[i] + ko, xb + xl_u[i]);
    }
    // compute tile t
    const char* xl = smem + (t % 3) * 16384;
    const char* wl = smem + 49152 + (t & 1) * 24576;
#pragma unroll
    for (int ks = 0; ks < 2; ks++) {
      int c0 = ks * 8 + g * 2;
      int rowb = (wm * 16 + r) * 256;
      f32x4 xa0 = *(const f32x4*)(xl + rowb + ((c0 ^ rs7) * 16));
      f32x4 xa1 = *(const f32x4*)(xl + rowb + (((c0 + 1) ^ rs7) * 16));
      union { unsigned u[4]; short8 v; } pk;
      asm("v_cvt_pk_bf16_f32 %0, %1, %2" : "=v"(pk.u[0]) : "v"(xa0[0]), "v"(xa0[1]));
      asm("v_cvt_pk_bf16_f32 %0, %1, %2" : "=v"(pk.u[1]) : "v"(xa0[2]), "v"(xa0[3]));
      asm("v_cvt_pk_bf16_f32 %0, %1, %2" : "=v"(pk.u[2]) : "v"(xa1[0]), "v"(xa1[1]));
      asm("v_cvt_pk_bf16_f32 %0, %1, %2" : "=v"(pk.u[3]) : "v"(xa1[2]), "v"(xa1[3]));
      short8 af = pk.v;
#pragma unroll
      for (int nf = 0; nf < 6; nf++) {
        int wrow = wn * 96 + nf * 16 + r;
        int wp = (ks * 4 + g) ^ rs7;
        short8 bf = *(const short8*)(wl + wrow * 128 + wp * 16);
        acc[nf] = MFMA16(af, bf, acc[nf]);
      }
    }
    // counted wait: keep x(t+2)'s 2 loads in flight; drain near the tail
    if (t < 14) asm volatile("s_waitcnt vmcnt(2)" ::: "memory");
    else        asm volatile("s_waitcnt vmcnt(0)" ::: "memory");
    __builtin_amdgcn_s_barrier();
  }
  // epilogue: row = row0 + wm*16 + g*4 + reg, col = wn*96 + nf*16 + r
#pragma unroll
  for (int nf = 0; nf < 6; nf++) {
    int col = wn * 96 + nf * 16 + r;
    if (col < 128) {
      int mat = col >> 6, h = col & 63;
      unsigned short* dst = (mat == 0) ? Kb : Qb;
#pragma unroll
      for (int reg = 0; reg < 4; reg++) {
        int grow = row0 + wm * 16 + g * 4 + reg;
        dst[(size_t)grow * 64 + h] = f2bf(acc[nf][reg]);
      }
    } else {
      int h = col & 63;
      int grow0 = row0 + wm * 16 + g * 4;
      unsigned short t4[4];
#pragma unroll
      for (int reg = 0; reg < 4; reg++) t4[reg] = f2bf(acc[nf][reg]);
      // sigma permutation within the 64-row block (reg stays contiguous)
      int kv6 = grow0 & 63;
      int nfb = (kv6 >> 4) & 3, gb = (kv6 >> 2) & 3;
      int s0 = (nfb >> 1) * 32 + gb * 8 + (nfb & 1) * 4;
      size_t off = ((size_t)(grow0 >> 12) * 64 + h) * 4096 +
                   ((size_t)(grow0 & 4095) & ~(size_t)63) + s0;
      *(short4v*)&Vt[off] = *(short4v*)t4;
    }
  }
}

// ---------------------------------------------------------------------------
// Kernel 2: causal flash attention v8 (= v6 loop + colocation-balanced qt).
// grid 512, 256 thr = 4 waves kv-split (t%4==w), 32-row q-tile.
// qt = (iq<64) ? 64+iq : 127-iq -> colocated pair (bi, bi+256) sums to 65
// tiles -> uniform per-CU work. Swapped QK^T + swapped PV with pi-permuted
// V; P in registers (cvt_pk). V loads after QK^T hide under softmax.
// ---------------------------------------------------------------------------
__global__ __launch_bounds__(256, 3) void attn_kernel(
    const unsigned short* __restrict__ Kb, const unsigned short* __restrict__ Qb,
    const unsigned short* __restrict__ VtB, float* __restrict__ out) {
  __shared__ float O_l[4][32][68];
  __shared__ float st_l[4][32][2];
  int tid = threadIdx.x;
  int w = tid >> 6, lane = tid & 63;
  int g = lane >> 4, r = lane & 15;
  int bi = blockIdx.x;
  int b = bi & 3, iq = bi >> 2;           // iq 0..127
  int qt = (iq < 64) ? (64 + iq) : (127 - iq);
  int qabs = qt * 32;
  const unsigned short* Kp = Kb + (size_t)b * 4096 * 64;
  const unsigned short* Qp = Qb + (size_t)b * 4096 * 64;
  const unsigned short* Vp = VtB + (size_t)b * 64 * 4096;

  // Q B-operand frags: B[q=mf*16+r][k=h=ks*32+g*8+j]
  short8 qa[2][2];
#pragma unroll
  for (int mf = 0; mf < 2; mf++)
#pragma unroll
    for (int ks = 0; ks < 2; ks++)
      qa[mf][ks] = *(const short8*)&Qp[(size_t)(qabs + mf * 16 + r) * 64 + ks * 32 + g * 8];

  float m_st[2] = {NEG_HUGE, NEG_HUGE};
  float l_ln[2] = {0.f, 0.f};        // per-lane partial row sums
  f32x4 o[4][2];                      // o[nfh][mf]
#pragma unroll
  for (int nfh = 0; nfh < 4; nfh++)
#pragma unroll
    for (int mf = 0; mf < 2; mf++) o[nfh][mf] = (f32x4){0.f, 0.f, 0.f, 0.f};

  int ntiles = (qabs >> 6) + 1;
  for (int t = w; t < ntiles; t += 4) {
    int kvb = t << 6;
    // ---- S^T = K Q^T, K loaded JIT per ks-half ----
    f32x4 s[4][2];
#pragma unroll
    for (int nf = 0; nf < 4; nf++)
#pragma unroll
      for (int mf = 0; mf < 2; mf++) s[nf][mf] = (f32x4){0.f, 0.f, 0.f, 0.f};
#pragma unroll
    for (int ks = 0; ks < 2; ks++) {
      short8 kf[4];
#pragma unroll
      for (int nf = 0; nf < 4; nf++)
        kf[nf] = *(const short8*)&Kp[(size_t)(kvb + nf * 16 + r) * 64 + ks * 32 + g * 8];
#pragma unroll
      for (int nf = 0; nf < 4; nf++) {
        s[nf][0] = MFMA16(kf[nf], qa[0][ks], s[nf][0]);
        s[nf][1] = MFMA16(kf[nf], qa[1][ks], s[nf][1]);
      }
    }
    // ---- V A-fragments issued here: latency hides under softmax ----
    short8 vf[2][4];
#pragma unroll
    for (int ks = 0; ks < 2; ks++)
#pragma unroll
      for (int nfh = 0; nfh < 4; nfh++)
        vf[ks][nfh] = *(const short8*)&Vp[(size_t)(nfh * 16 + r) * 4096 + kvb + ks * 32 + g * 8];
    // ---- causal mask (final tile only) ----
    if (kvb + 63 > qabs) {
#pragma unroll
      for (int mf = 0; mf < 2; mf++) {
        int q = qabs + mf * 16 + r;
#pragma unroll
        for (int nf = 0; nf < 4; nf++)
#pragma unroll
          for (int reg = 0; reg < 4; reg++) {
            int kv = kvb + nf * 16 + g * 4 + reg;
            if (kv > q) s[nf][mf][reg] = NEG_HUGE;
          }
      }
    }
    // ---- row max (in-lane 16 + xor16/xor32), alpha ----
    float alpha[2];
#pragma unroll
    for (int mf = 0; mf < 2; mf++) {
      float m0 = fmaxf(fmaxf(fmaxf(s[0][mf][0], s[0][mf][1]), fmaxf(s[0][mf][2], s[0][mf][3])),
                       fmaxf(fmaxf(s[1][mf][0], s[1][mf][1]), fmaxf(s[1][mf][2], s[1][mf][3])));
      float m1 = fmaxf(fmaxf(fmaxf(s[2][mf][0], s[2][mf][1]), fmaxf(s[2][mf][2], s[2][mf][3])),
                       fmaxf(fmaxf(s[3][mf][0], s[3][mf][1]), fmaxf(s[3][mf][2], s[3][mf][3])));
      float m0a = fmaxf(m0, m1);
      m0a = fmaxf(m0a, __shfl_xor(m0a, 16));
      m0a = fmaxf(m0a, __shfl_xor(m0a, 32));
      float mn = fmaxf(m_st[mf], m0a);
      alpha[mf] = exp2f(m_st[mf] - mn);
      m_st[mf] = mn;
    }
    // ---- P = exp2(S - m) in-place; per-lane partial sums; rescale O ----
#pragma unroll
    for (int mf = 0; mf < 2; mf++) {
      float rs = 0.f;
#pragma unroll
      for (int nf = 0; nf < 4; nf++)
#pragma unroll
        for (int reg = 0; reg < 4; reg++) {
          float p = exp2f(s[nf][mf][reg] - m_st[mf]);
          s[nf][mf][reg] = p;
          rs += p;
        }
      l_ln[mf] = l_ln[mf] * alpha[mf] + rs;
#pragma unroll
      for (int nfh = 0; nfh < 4; nfh++)
#pragma unroll
        for (int reg = 0; reg < 4; reg++) o[nfh][mf][reg] *= alpha[mf];
    }
    // ---- pack P lane-locally (pi layout) and PV ----
#pragma unroll
    for (int ks = 0; ks < 2; ks++)
#pragma unroll
      for (int mf = 0; mf < 2; mf++) {
        union { unsigned u[4]; short8 v; } pb;
        asm("v_cvt_pk_bf16_f32 %0, %1, %2" : "=v"(pb.u[0]) : "v"(s[2 * ks][mf][0]), "v"(s[2 * ks][mf][1]));
        asm("v_cvt_pk_bf16_f32 %0, %1, %2" : "=v"(pb.u[1]) : "v"(s[2 * ks][mf][2]), "v"(s[2 * ks][mf][3]));
        asm("v_cvt_pk_bf16_f32 %0, %1, %2" : "=v"(pb.u[2]) : "v"(s[2 * ks + 1][mf][0]), "v"(s[2 * ks + 1][mf][1]));
        asm("v_cvt_pk_bf16_f32 %0, %1, %2" : "=v"(pb.u[3]) : "v"(s[2 * ks + 1][mf][2]), "v"(s[2 * ks + 1][mf][3]));
#pragma unroll
        for (int nfh = 0; nfh < 4; nfh++)
          o[nfh][mf] = MFMA16(vf[ks][nfh], pb.v, o[nfh][mf]);
      }
  }
  // ---- finalize l (deferred reduction) ----
#pragma unroll
  for (int mf = 0; mf < 2; mf++) {
    float s0 = l_ln[mf];
    s0 += __shfl_xor(s0, 16);
    s0 += __shfl_xor(s0, 32);
    l_ln[mf] = s0;
  }
  // ---- cross-wave merge: store [q][h] (q = mf*16+r, h = nfh*16+g*4+reg) ----
  __syncthreads();
#pragma unroll
  for (int nfh = 0; nfh < 4; nfh++)
#pragma unroll
    for (int mf = 0; mf < 2; mf++)
      *(f32x4*)&O_l[w][mf * 16 + r][nfh * 16 + g * 4] = o[nfh][mf];
  if (g == 0) {
#pragma unroll
    for (int mf = 0; mf < 2; mf++) {
      st_l[w][mf * 16 + r][0] = m_st[mf];
      st_l[w][mf * 16 + r][1] = l_ln[mf];
    }
  }
  __syncthreads();
  {
    int row = tid >> 3, cg = tid & 7;   // row = q (0..31), cg*8 = h block
    float mw[4], lw[4];
#pragma unroll
    for (int ww = 0; ww < 4; ww++) {
      mw[ww] = st_l[ww][row][0];
      lw[ww] = st_l[ww][row][1];
    }
    float mstar = fmaxf(fmaxf(mw[0], mw[1]), fmaxf(mw[2], mw[3]));
    float sc[4], lstar = 0.f;
#pragma unroll
    for (int ww = 0; ww < 4; ww++) { sc[ww] = exp2f(mw[ww] - mstar); lstar += sc[ww] * lw[ww]; }
    float inv = 1.0f / lstar;
    float a0[8];
#pragma unroll
    for (int cc = 0; cc < 8; cc++) a0[cc] = 0.f;
#pragma unroll
    for (int ww = 0; ww < 4; ww++) {
      f32x4 v0 = *(f32x4*)&O_l[ww][row][cg * 8];
      f32x4 v1 = *(f32x4*)&O_l[ww][row][cg * 8 + 4];
#pragma unroll
      for (int e = 0; e < 4; e++) { a0[e] += sc[ww] * v0[e]; a0[4 + e] += sc[ww] * v1[e]; }
    }
    float4v o0, o1;
#pragma unroll
    for (int e = 0; e < 4; e++) { o0[e] = a0[e] * inv; o1[e] = a0[4 + e] * inv; }
    float* op = &out[((size_t)b * 4096 + qabs + row) * 64 + cg * 8];
    *(float4v*)op = o0;
    *(float4v*)(op + 4) = o1;
  }
}

// ---------------------------------------------------------------------------
extern "C" void kernel_launch(void* const* d_in, const int* in_sizes, int n_in,
                              void* d_out, int out_size, void* d_ws, size_t ws_size,
                              hipStream_t stream) {
  (void)in_sizes; (void)n_in; (void)out_size; (void)ws_size;
  const float* x  = (const float*)d_in[0];
  const float* Wk = (const float*)d_in[1];
  const float* Wq = (const float*)d_in[2];
  const float* Wv = (const float*)d_in[3];
  float* out = (float*)d_out;
  char* ws = (char*)d_ws;

  unsigned short* Wt = (unsigned short*)ws;                       // 384KB
  unsigned short* Kb = (unsigned short*)(ws + (512u << 10));      // 2MB
  unsigned short* Qb = (unsigned short*)(ws + (512u << 10) + (2u << 20));
  unsigned short* Vt = (unsigned short*)(ws + (512u << 10) + (4u << 20));

  wtrans_kernel<<<48, 256, 0, stream>>>(Wk, Wq, Wv, Wt);
  proj_kernel<<<256, 512, 98304, stream>>>(x, Wt, Kb, Qb, Vt);
  attn_kernel<<<512, 256, 0, stream>>>(Kb, Qb, Vt, out);
}